// Round 2
// baseline (1249.547 us; speedup 1.0000x reference)
//
#include <hip/hip_runtime.h>

#define NN 128
#define NITER 300
#define NSTEP 14   // safeguarded-Newton steps (bracket-clamped); superlinear on
                   // piecewise-linear s(tau) -> active set matches 50-step ref bisection

// ---- DPP wave-64 reductions (VALU pipe, no LDS traffic) ----
template<int CTRL>
__device__ __forceinline__ float dpp0(float x) {  // invalid lanes contribute 0
  return __int_as_float(__builtin_amdgcn_update_dpp(0, __float_as_int(x), CTRL, 0xF, 0xF, true));
}
template<int CTRL>
__device__ __forceinline__ float dppS(float x) {  // invalid lanes keep self
  int xi = __float_as_int(x);
  return __int_as_float(__builtin_amdgcn_update_dpp(xi, xi, CTRL, 0xF, 0xF, false));
}
__device__ __forceinline__ float bcast63(float x) {
  return __int_as_float(__builtin_amdgcn_readlane(__float_as_int(x), 63));
}
__device__ __forceinline__ float rlane(float x, int l) {   // l must be literal/uniform
  return __int_as_float(__builtin_amdgcn_readlane(__float_as_int(x), l));
}
__device__ __forceinline__ float wsum(float x) {
  x += dpp0<0x111>(x); x += dpp0<0x112>(x); x += dpp0<0x114>(x);
  x += dpp0<0x118>(x); x += dpp0<0x142>(x); x += dpp0<0x143>(x);
  return bcast63(x);
}
// two independent sums, chains interleaved to hide DPP latency
__device__ __forceinline__ void wsum2(float& x, float& y) {
  float a = x, b = y;
  a += dpp0<0x111>(a); b += dpp0<0x111>(b);
  a += dpp0<0x112>(a); b += dpp0<0x112>(b);
  a += dpp0<0x114>(a); b += dpp0<0x114>(b);
  a += dpp0<0x118>(a); b += dpp0<0x118>(b);
  a += dpp0<0x142>(a); b += dpp0<0x142>(b);
  a += dpp0<0x143>(a); b += dpp0<0x143>(b);
  x = bcast63(a); y = bcast63(b);
}
__device__ __forceinline__ float wmin(float x) {
  x = fminf(x, dppS<0x111>(x)); x = fminf(x, dppS<0x112>(x));
  x = fminf(x, dppS<0x114>(x)); x = fminf(x, dppS<0x118>(x));
  x = fminf(x, dppS<0x142>(x)); x = fminf(x, dppS<0x143>(x));
  return bcast63(x);
}
__device__ __forceinline__ float wmax(float x) {
  x = fmaxf(x, dppS<0x111>(x)); x = fmaxf(x, dppS<0x112>(x));
  x = fmaxf(x, dppS<0x114>(x)); x = fmaxf(x, dppS<0x118>(x));
  x = fmaxf(x, dppS<0x142>(x)); x = fmaxf(x, dppS<0x143>(x));
  return bcast63(x);
}

__global__ __attribute__((amdgpu_flat_work_group_size(256, 256),
                          amdgpu_waves_per_eu(4, 4)))   // pin 4 waves/EU -> 128-VGPR budget
void markowitz_kernel(const float* __restrict__ rets,
                      const float* __restrict__ cov,
                      const float* __restrict__ gam,
                      const float* __restrict__ alp,
                      float* __restrict__ out)
{
  __shared__ float yL[NN];
  __shared__ float wLs[NN];
  __shared__ float pL[2][NN];
  __shared__ float red[4];

  const int b    = blockIdx.x;
  const int t    = threadIdx.x;
  const int lane = t & 63;
  const int wid  = t >> 6;
  const int rh   = wid & 1;          // row half (0/1)
  const int ch   = wid >> 1;         // col half (0/1)
  const int row  = rh * 64 + lane;   // this thread's matvec row

  const float g   = gam[b];
  const float g2  = g * g;
  const float aab = fabsf(alp[b]);
  const float* cb = cov + (size_t)b * (NN * NN);

  // ---------- build: acc[u] = (C^T C)[row][64*ch+u], straight from global ----------
  // per k: lane-coalesced 256B loads of C[k][rowhalf] and C[k][colhalf];
  // column values broadcast via v_readlane (SGPR operand on v_fmac).
  float acc[64];
  #pragma unroll
  for (int u = 0; u < 64; ++u) acc[u] = 0.f;

  const float* arow = cb + rh * 64 + lane;
  const float* brow = cb + ch * 64 + lane;
  #pragma unroll 2
  for (int k = 0; k < NN; ++k) {
    float a  = arow[k * NN];      // C[k][row]
    float bb = brow[k * NN];      // C[k][64*ch+lane]
    #pragma unroll
    for (int u = 0; u < 64; ++u)
      acc[u] = fmaf(a, rlane(bb, u), acc[u]);
  }

  // finish Q2 = 2*step*(g2*C^T C + aab*I); Frobenius first
  float ss = 0.f;
  #pragma unroll
  for (int u = 0; u < 64; ++u) {
    float q = g2 * acc[u];
    if (64 * ch + u == row) q += aab;   // row is runtime but u literal -> cndmask, no dyn index
    acc[u] = q;
    ss = fmaf(q, q, ss);
  }
  float ssw = wsum(ss);
  if (lane == 0) red[wid] = ssw;
  __syncthreads();
  const float S    = (red[0] + red[1]) + (red[2] + red[3]);
  const float step = 0.5f / sqrtf(S);      // 1 / (2*||Q||_F)
  const float sc   = 2.f * step;
  #pragma unroll
  for (int u = 0; u < 64; ++u) acc[u] *= sc;

  const float r2a = step * rets[b * NN + lane];        // step*rets, coord lane
  const float r2b = step * rets[b * NN + 64 + lane];   // coord lane+64

  if (t < NN) { yL[t] = 1.f / 128.f; wLs[t] = 1.f / 128.f; }
  __syncthreads();

  // ---------- FISTA ----------
  float t_f = 1.f;
  const int ownbase = (b >> 8) & 3;   // co-resident blocks differ in b>>8 -> owner on distinct SIMDs

  for (int it = 0; it < NITER; ++it) {
    // matvec partial: p = Q2[row][64ch..] . y[64ch..]; y via one ds_read + readlane bcast
    float yv = yL[64 * ch + lane];
    float p0 = 0.f, p1 = 0.f, p2 = 0.f, p3 = 0.f;
    #pragma unroll
    for (int u = 0; u < 64; u += 4) {
      p0 = fmaf(acc[u + 0], rlane(yv, u + 0), p0);
      p1 = fmaf(acc[u + 1], rlane(yv, u + 1), p1);
      p2 = fmaf(acc[u + 2], rlane(yv, u + 2), p2);
      p3 = fmaf(acc[u + 3], rlane(yv, u + 3), p3);
    }
    pL[ch][row] = (p0 + p1) + (p2 + p3);
    __syncthreads();

    if (wid == ((it + ownbase) & 3)) {
      // owner wave: projection of v = y - step*grad, 2 coords/lane
      float y0 = yL[lane],      y1 = yL[64 + lane];
      float q0 = pL[0][lane]      + pL[1][lane];
      float q1 = pL[0][64 + lane] + pL[1][64 + lane];
      float v0 = y0 - q0 + r2a;
      float v1 = y1 - q1 + r2b;

      float lo = wmin(fminf(v0, v1)) - 1.0f;
      float hi = wmax(fmaxf(v0, v1));
      float tau = 0.5f * (lo + hi);
      #pragma unroll 1
      for (int s2 = 0; s2 < NSTEP; ++s2) {
        float z0 = v0 - tau, z1 = v1 - tau;
        float c0 = __builtin_amdgcn_fmed3f(z0, 0.f, 1.f);
        float c1 = __builtin_amdgcn_fmed3f(z1, 0.f, 1.f);
        float f0 = (c0 > 0.f && c0 < 1.f) ? 1.f : 0.f;
        float f1 = (c1 > 0.f && c1 < 1.f) ? 1.f : 0.f;
        float s = c0 + c1, nf = f0 + f1;
        wsum2(s, nf);                       // two interleaved DPP chains
        bool gt = (s > 1.f);
        lo = gt ? tau : lo;
        hi = gt ? hi : tau;
        // Newton on s(tau)=1 (slope -nf), clamped into bracket
        float tn = fmaf(s - 1.f, __builtin_amdgcn_rcpf(fmaxf(nf, 1.f)), tau);
        tau = (tn > lo && tn < hi) ? tn : 0.5f * (lo + hi);
      }
      float tau0 = 0.5f * (lo + hi);
      float z0 = v0 - tau0, z1 = v1 - tau0;
      bool f0 = (z0 > 0.f) && (z0 < 1.0f);
      bool f1 = (z1 > 0.f) && (z1 < 1.0f);
      bool cap0 = (z0 >= 1.0f), cap1 = (z1 >= 1.0f);
      float sfv = (f0 ? v0 : 0.f) + (f1 ? v1 : 0.f);
      float cnt = (f0 ? 1.f : 0.f) + (f1 ? 1.f : 0.f)
                + 1024.f * ((cap0 ? 1.f : 0.f) + (cap1 ? 1.f : 0.f));
      wsum2(sfv, cnt);
      float nu = floorf(cnt * (1.f / 1024.f));
      float nfree = fmaxf(cnt - 1024.f * nu, 1.f);
      float tauf = (sfv + nu - 1.f) / nfree;     // mw = 1
      float w0 = f0 ? (v0 - tauf) : (cap0 ? 1.0f : 0.f);
      float w1 = f1 ? (v1 - tauf) : (cap1 ? 1.0f : 0.f);

      float tn   = 0.5f * (1.f + sqrtf(1.f + 4.f * t_f * t_f));
      float coef = (t_f - 1.f) / tn;
      float wp0 = wLs[lane], wp1 = wLs[64 + lane];
      yL[lane]       = w0 + coef * (w0 - wp0);
      yL[64 + lane]  = w1 + coef * (w1 - wp1);
      wLs[lane] = w0;  wLs[64 + lane] = w1;
    }
    t_f = 0.5f * (1.f + sqrtf(1.f + 4.f * t_f * t_f));  // all waves track t
    __syncthreads();
  }

  if (t < NN) out[(size_t)b * NN + t] = wLs[t];
}

extern "C" void kernel_launch(void* const* d_in, const int* in_sizes, int n_in,
                              void* d_out, int out_size, void* d_ws, size_t ws_size,
                              hipStream_t stream) {
  (void)n_in; (void)d_ws; (void)ws_size; (void)out_size;
  const float* rets = (const float*)d_in[0];
  const float* cov  = (const float*)d_in[1];
  const float* gam  = (const float*)d_in[2];
  const float* alp  = (const float*)d_in[3];
  float* out = (float*)d_out;
  const int B = in_sizes[0] / NN;   // 1024
  markowitz_kernel<<<B, 256, 0, stream>>>(rets, cov, gam, alp, out);
}